// Round 1
// baseline (2835.769 us; speedup 1.0000x reference)
//
#include <hip/hip_runtime.h>
#include <math.h>

// GraphSAGE 2-layer, N=100000 nodes, E=3200000 edges
// IN=128, H1=32, H2=20, NCLS=10

__global__ __launch_bounds__(256) void k_lin1(
    const float* __restrict__ x, const float* __restrict__ W1l,
    const float* __restrict__ W1r, float* __restrict__ y1,
    float* __restrict__ r1, int n_nodes)
{
    int n = blockIdx.x * 256 + threadIdx.x;
    if (n >= n_nodes) return;
    float accL[32], accR[32];
#pragma unroll
    for (int j = 0; j < 32; ++j) { accL[j] = 0.f; accR[j] = 0.f; }
    const float4* x4 = reinterpret_cast<const float4*>(x) + (size_t)n * 32;
    for (int k4 = 0; k4 < 32; ++k4) {
        float4 xv = x4[k4];
        const float* wl = W1l + k4 * 4 * 32;   // wave-uniform -> s_load
        const float* wr = W1r + k4 * 4 * 32;
#pragma unroll
        for (int j = 0; j < 32; ++j) {
            float a = accL[j];
            a = fmaf(xv.x, wl[j],      a);
            a = fmaf(xv.y, wl[32 + j], a);
            a = fmaf(xv.z, wl[64 + j], a);
            a = fmaf(xv.w, wl[96 + j], a);
            accL[j] = a;
            float b = accR[j];
            b = fmaf(xv.x, wr[j],      b);
            b = fmaf(xv.y, wr[32 + j], b);
            b = fmaf(xv.z, wr[64 + j], b);
            b = fmaf(xv.w, wr[96 + j], b);
            accR[j] = b;
        }
    }
    float4* yo = reinterpret_cast<float4*>(y1 + (size_t)n * 32);
    float4* ro = reinterpret_cast<float4*>(r1 + (size_t)n * 32);
#pragma unroll
    for (int q = 0; q < 8; ++q) {
        yo[q] = make_float4(accL[q*4], accL[q*4+1], accL[q*4+2], accL[q*4+3]);
        ro[q] = make_float4(accR[q*4], accR[q*4+1], accR[q*4+2], accR[q*4+3]);
    }
}

// 8 threads per edge: each handles one float4 of the 32-float row
__global__ __launch_bounds__(256) void k_scatter1(
    const int* __restrict__ src, const int* __restrict__ dst,
    const float* __restrict__ y1, float* __restrict__ agg1,
    float* __restrict__ deg, int n_edges)
{
    unsigned long long t = (unsigned long long)blockIdx.x * 256 + threadIdx.x;
    unsigned int e = (unsigned int)(t >> 3);
    unsigned int c = (unsigned int)(t & 7);
    if (e >= (unsigned int)n_edges) return;
    int s = src[e], d = dst[e];
    float4 v = reinterpret_cast<const float4*>(y1)[(size_t)s * 8 + c];
    float* ap = agg1 + (size_t)d * 32 + c * 4;
    atomicAdd(ap + 0, v.x);
    atomicAdd(ap + 1, v.y);
    atomicAdd(ap + 2, v.z);
    atomicAdd(ap + 3, v.w);
    if (c == 0) atomicAdd(deg + d, 1.0f);
}

__global__ __launch_bounds__(256) void k_combine1(
    const float* __restrict__ agg1, const float* __restrict__ r1,
    const float* __restrict__ deg, const float* __restrict__ b1,
    const float* __restrict__ W2l, const float* __restrict__ W2r,
    float* __restrict__ z2, float* __restrict__ r2, int n_nodes)
{
    int n = blockIdx.x * 256 + threadIdx.x;
    if (n >= n_nodes) return;
    float inv = 1.0f / fmaxf(deg[n], 1.0f);
    float h[32];
    float ss = 0.f;
    const float4* a4 = reinterpret_cast<const float4*>(agg1 + (size_t)n * 32);
    const float4* r4 = reinterpret_cast<const float4*>(r1 + (size_t)n * 32);
#pragma unroll
    for (int q = 0; q < 8; ++q) {
        float4 a = a4[q];
        float4 r = r4[q];
        float v0 = fmaf(a.x, inv, b1[q*4+0] + r.x);
        float v1 = fmaf(a.y, inv, b1[q*4+1] + r.y);
        float v2 = fmaf(a.z, inv, b1[q*4+2] + r.z);
        float v3 = fmaf(a.w, inv, b1[q*4+3] + r.w);
        h[q*4+0] = v0; h[q*4+1] = v1; h[q*4+2] = v2; h[q*4+3] = v3;
        ss += v0*v0 + v1*v1 + v2*v2 + v3*v3;
    }
    float nrm = fmaxf(sqrtf(ss), 1e-12f);
    float innrm = 1.0f / nrm;
#pragma unroll
    for (int i = 0; i < 32; ++i) h[i] = fmaxf(h[i] * innrm, 0.f);
    // project to layer-2 space: z2 = h @ W2l, r2 = h @ W2r
    float acc[40];
#pragma unroll
    for (int j = 0; j < 40; ++j) acc[j] = 0.f;
    for (int i = 0; i < 32; ++i) {
        float hv = h[i];
        const float* wl = W2l + i * 20;   // uniform -> scalar loads
        const float* wr = W2r + i * 20;
#pragma unroll
        for (int j = 0; j < 20; ++j) {
            acc[j]      = fmaf(hv, wl[j], acc[j]);
            acc[20 + j] = fmaf(hv, wr[j], acc[20 + j]);
        }
    }
    float4* zo = reinterpret_cast<float4*>(z2 + (size_t)n * 20);
    float4* ro = reinterpret_cast<float4*>(r2 + (size_t)n * 20);
#pragma unroll
    for (int q = 0; q < 5; ++q) {
        zo[q] = make_float4(acc[q*4], acc[q*4+1], acc[q*4+2], acc[q*4+3]);
        ro[q] = make_float4(acc[20+q*4], acc[20+q*4+1], acc[20+q*4+2], acc[20+q*4+3]);
    }
}

// 5 threads per edge: each handles one float4 of the 20-float row
__global__ __launch_bounds__(256) void k_scatter2(
    const int* __restrict__ src, const int* __restrict__ dst,
    const float* __restrict__ z2, float* __restrict__ agg2, int n_edges)
{
    unsigned long long t64 = (unsigned long long)blockIdx.x * 256 + threadIdx.x;
    unsigned int t = (unsigned int)t64;
    unsigned int e = t / 5u;
    unsigned int c = t - e * 5u;
    if (e >= (unsigned int)n_edges) return;
    int s = src[e], d = dst[e];
    float4 v = reinterpret_cast<const float4*>(z2)[(size_t)s * 5 + c];
    float* ap = agg2 + (size_t)d * 20 + c * 4;
    atomicAdd(ap + 0, v.x);
    atomicAdd(ap + 1, v.y);
    atomicAdd(ap + 2, v.z);
    atomicAdd(ap + 3, v.w);
}

__global__ __launch_bounds__(256) void k_combine2(
    const float* __restrict__ agg2, const float* __restrict__ r2,
    const float* __restrict__ deg, const float* __restrict__ b2,
    const float* __restrict__ Wout, const float* __restrict__ bout,
    float* __restrict__ out, int n_nodes)
{
    int n = blockIdx.x * 256 + threadIdx.x;
    if (n >= n_nodes) return;
    float inv = 1.0f / fmaxf(deg[n], 1.0f);
    float o[20];
    float ss = 0.f;
    const float4* a4 = reinterpret_cast<const float4*>(agg2 + (size_t)n * 20);
    const float4* r4 = reinterpret_cast<const float4*>(r2 + (size_t)n * 20);
#pragma unroll
    for (int q = 0; q < 5; ++q) {
        float4 a = a4[q];
        float4 r = r4[q];
        float v0 = fmaf(a.x, inv, b2[q*4+0] + r.x);
        float v1 = fmaf(a.y, inv, b2[q*4+1] + r.y);
        float v2 = fmaf(a.z, inv, b2[q*4+2] + r.z);
        float v3 = fmaf(a.w, inv, b2[q*4+3] + r.w);
        o[q*4+0] = v0; o[q*4+1] = v1; o[q*4+2] = v2; o[q*4+3] = v3;
        ss += v0*v0 + v1*v1 + v2*v2 + v3*v3;
    }
    float nrm = fmaxf(sqrtf(ss), 1e-12f);
    float innrm = 1.0f / nrm;
    float l[10];
#pragma unroll
    for (int c = 0; c < 10; ++c) l[c] = bout[c];
    for (int i = 0; i < 20; ++i) {
        float ov = o[i] * innrm;
        const float* wr = Wout + i * 10;  // uniform -> scalar loads
#pragma unroll
        for (int c = 0; c < 10; ++c) l[c] = fmaf(ov, wr[c], l[c]);
    }
    float m = l[0];
#pragma unroll
    for (int c = 1; c < 10; ++c) m = fmaxf(m, l[c]);
    float s = 0.f;
    float ex[10];
#pragma unroll
    for (int c = 0; c < 10; ++c) { ex[c] = expf(l[c] - m); s += ex[c]; }
    float is = 1.0f / s;
    float* op = out + (size_t)n * 10;
#pragma unroll
    for (int c = 0; c < 10; ++c) op[c] = ex[c] * is;
}

extern "C" void kernel_launch(void* const* d_in, const int* in_sizes, int n_in,
                              void* d_out, int out_size, void* d_ws, size_t ws_size,
                              hipStream_t stream)
{
    const float* x    = (const float*)d_in[0];
    const int*   ei   = (const int*)d_in[1];
    const float* W1l  = (const float*)d_in[2];
    const float* b1   = (const float*)d_in[3];
    const float* W1r  = (const float*)d_in[4];
    const float* W2l  = (const float*)d_in[5];
    const float* b2   = (const float*)d_in[6];
    const float* W2r  = (const float*)d_in[7];
    const float* Wout = (const float*)d_in[8];
    const float* bout = (const float*)d_in[9];
    float* out = (float*)d_out;

    int n_nodes = in_sizes[0] / 128;
    int n_edges = in_sizes[1] / 2;
    const int* src = ei;
    const int* dst = ei + n_edges;

    float* ws   = (float*)d_ws;
    float* agg1 = ws;                              // N*32
    float* agg2 = agg1 + (size_t)n_nodes * 32;     // N*20
    float* deg  = agg2 + (size_t)n_nodes * 20;     // N
    float* y1   = deg  + n_nodes;                  // N*32
    float* r1   = y1   + (size_t)n_nodes * 32;     // N*32
    float* z2   = r1   + (size_t)n_nodes * 32;     // N*20
    float* r2   = z2   + (size_t)n_nodes * 20;     // N*20

    size_t zero_bytes = (size_t)n_nodes * (32 + 20 + 1) * sizeof(float);
    hipMemsetAsync(d_ws, 0, zero_bytes, stream);

    int nb = (n_nodes + 255) / 256;
    k_lin1<<<nb, 256, 0, stream>>>(x, W1l, W1r, y1, r1, n_nodes);

    long long t1 = (long long)n_edges * 8;
    k_scatter1<<<(int)((t1 + 255) / 256), 256, 0, stream>>>(src, dst, y1, agg1, deg, n_edges);

    k_combine1<<<nb, 256, 0, stream>>>(agg1, r1, deg, b1, W2l, W2r, z2, r2, n_nodes);

    long long t2 = (long long)n_edges * 5;
    k_scatter2<<<(int)((t2 + 255) / 256), 256, 0, stream>>>(src, dst, z2, agg2, n_edges);

    k_combine2<<<nb, 256, 0, stream>>>(agg2, r2, deg, b2, Wout, bout, out, n_nodes);
}

// Round 2
// 1117.168 us; speedup vs baseline: 2.5384x; 2.5384x over previous
//
#include <hip/hip_runtime.h>
#include <math.h>

// GraphSAGE 2-layer, N=100000 nodes, E=3200000 edges
// IN=128, H1=32, H2=20, NCLS=10
// Strategy: aggregate in OUTPUT feature space (linearity commutes with
// segment-mean), and replace fp32 scatter-atomics with CSR build + gather.

__global__ __launch_bounds__(256) void k_lin1(
    const float* __restrict__ x, const float* __restrict__ W1l,
    const float* __restrict__ W1r, float* __restrict__ y1,
    float* __restrict__ r1, int n_nodes)
{
    int n = blockIdx.x * 256 + threadIdx.x;
    if (n >= n_nodes) return;
    float accL[32], accR[32];
#pragma unroll
    for (int j = 0; j < 32; ++j) { accL[j] = 0.f; accR[j] = 0.f; }
    const float4* x4 = reinterpret_cast<const float4*>(x) + (size_t)n * 32;
    for (int k4 = 0; k4 < 32; ++k4) {
        float4 xv = x4[k4];
        const float* wl = W1l + k4 * 4 * 32;   // wave-uniform -> scalar loads
        const float* wr = W1r + k4 * 4 * 32;
#pragma unroll
        for (int j = 0; j < 32; ++j) {
            float a = accL[j];
            a = fmaf(xv.x, wl[j],      a);
            a = fmaf(xv.y, wl[32 + j], a);
            a = fmaf(xv.z, wl[64 + j], a);
            a = fmaf(xv.w, wl[96 + j], a);
            accL[j] = a;
            float b = accR[j];
            b = fmaf(xv.x, wr[j],      b);
            b = fmaf(xv.y, wr[32 + j], b);
            b = fmaf(xv.z, wr[64 + j], b);
            b = fmaf(xv.w, wr[96 + j], b);
            accR[j] = b;
        }
    }
    float4* yo = reinterpret_cast<float4*>(y1 + (size_t)n * 32);
    float4* ro = reinterpret_cast<float4*>(r1 + (size_t)n * 32);
#pragma unroll
    for (int q = 0; q < 8; ++q) {
        yo[q] = make_float4(accL[q*4], accL[q*4+1], accL[q*4+2], accL[q*4+3]);
        ro[q] = make_float4(accR[q*4], accR[q*4+1], accR[q*4+2], accR[q*4+3]);
    }
}

// ---- CSR build ----
__global__ __launch_bounds__(256) void k_hist(
    const int* __restrict__ dst, int* __restrict__ cnt, int n_edges)
{
    int e = blockIdx.x * 256 + threadIdx.x;
    if (e < n_edges) atomicAdd(&cnt[dst[e]], 1);
}

__global__ __launch_bounds__(1024) void k_scan(
    const int* __restrict__ cnt, int* __restrict__ row_ptr,
    int* __restrict__ cursor, int n)
{
    __shared__ int sums[1024];
    int t = threadIdx.x;
    int chunk = (n + 1023) / 1024;
    int lo = t * chunk;
    int hi = lo + chunk; if (hi > n) hi = n;
    if (lo > n) lo = n;
    int s = 0;
    for (int i = lo; i < hi; ++i) s += cnt[i];
    sums[t] = s;
    __syncthreads();
    for (int off = 1; off < 1024; off <<= 1) {
        int o = (t >= off) ? sums[t - off] : 0;
        __syncthreads();
        sums[t] += o;
        __syncthreads();
    }
    int run = sums[t] - s;  // exclusive prefix
    for (int i = lo; i < hi; ++i) {
        row_ptr[i] = run;
        cursor[i]  = run;
        run += cnt[i];
    }
    if (hi == n) row_ptr[n] = run;  // threads past the end write total too (same value)
}

__global__ __launch_bounds__(256) void k_fill(
    const int* __restrict__ src, const int* __restrict__ dst,
    int* __restrict__ cursor, int* __restrict__ eid, int n_edges)
{
    int e = blockIdx.x * 256 + threadIdx.x;
    if (e >= n_edges) return;
    int d = dst[e];
    int pos = atomicAdd(&cursor[d], 1);
    eid[pos] = src[e];
}

// ---- Layer 1: gather-sum y1 over incoming edges, combine, normalize, relu,
//      project through W2l/W2r. 32 lanes per node (lane = channel). ----
__global__ __launch_bounds__(256) void k_agg1(
    const int* __restrict__ row_ptr, const int* __restrict__ eid,
    const float* __restrict__ y1, const float* __restrict__ r1,
    const float* __restrict__ b1, const float* __restrict__ W2l,
    const float* __restrict__ W2r,
    float* __restrict__ z2, float* __restrict__ r2, int n_nodes)
{
    int t = blockIdx.x * 256 + threadIdx.x;
    int n = t >> 5;
    int ch = t & 31;
    if (n >= n_nodes) return;
    int beg = row_ptr[n], end = row_ptr[n + 1];
    float sum = 0.f;
    for (int i = beg; i < end; ++i) {
        int s = eid[i];                      // same addr across 32 lanes -> broadcast
        sum += y1[(size_t)s * 32 + ch];      // 128B coalesced line per edge
    }
    float inv = 1.0f / fmaxf((float)(end - beg), 1.0f);
    float v = fmaf(sum, inv, b1[ch] + r1[(size_t)n * 32 + ch]);
    float ss = v * v;
#pragma unroll
    for (int off = 16; off >= 1; off >>= 1) ss += __shfl_xor(ss, off, 32);
    float h = fmaxf(v / fmaxf(sqrtf(ss), 1e-12f), 0.f);
    // projection: lanes 0..19 own output column j
    float accl = 0.f, accr = 0.f;
#pragma unroll 4
    for (int i = 0; i < 32; ++i) {
        float hv = __shfl(h, i, 32);
        if (ch < 20) {
            accl = fmaf(hv, W2l[i * 20 + ch], accl);
            accr = fmaf(hv, W2r[i * 20 + ch], accr);
        }
    }
    if (ch < 20) {
        z2[(size_t)n * 20 + ch] = accl;
        r2[(size_t)n * 20 + ch] = accr;
    }
}

// ---- Layer 2: gather-sum z2, combine, normalize, W_out, softmax. ----
__global__ __launch_bounds__(256) void k_agg2(
    const int* __restrict__ row_ptr, const int* __restrict__ eid,
    const float* __restrict__ z2, const float* __restrict__ r2,
    const float* __restrict__ b2, const float* __restrict__ Wout,
    const float* __restrict__ bout,
    float* __restrict__ out, int n_nodes)
{
    int t = blockIdx.x * 256 + threadIdx.x;
    int n = t >> 5;
    int ch = t & 31;
    if (n >= n_nodes) return;
    int beg = row_ptr[n], end = row_ptr[n + 1];
    bool act = ch < 20;
    float sum = 0.f;
    for (int i = beg; i < end; ++i) {
        int s = eid[i];
        if (act) sum += z2[(size_t)s * 20 + ch];
    }
    float inv = 1.0f / fmaxf((float)(end - beg), 1.0f);
    float v = act ? fmaf(sum, inv, b2[ch] + r2[(size_t)n * 20 + ch]) : 0.f;
    float ss = v * v;
#pragma unroll
    for (int off = 16; off >= 1; off >>= 1) ss += __shfl_xor(ss, off, 32);
    float o = v / fmaxf(sqrtf(ss), 1e-12f);
    float acc = (ch < 10) ? bout[ch] : 0.f;
#pragma unroll 4
    for (int i = 0; i < 20; ++i) {
        float ov = __shfl(o, i, 32);
        if (ch < 10) acc = fmaf(ov, Wout[i * 10 + ch], acc);
    }
    float lm = (ch < 10) ? acc : -1e30f;
    float m = lm;
#pragma unroll
    for (int off = 8; off >= 1; off >>= 1) m = fmaxf(m, __shfl_xor(m, off, 16));
    float ex = (ch < 10) ? expf(acc - m) : 0.f;
    float s2 = ex;
#pragma unroll
    for (int off = 8; off >= 1; off >>= 1) s2 += __shfl_xor(s2, off, 16);
    if (ch < 10) out[(size_t)n * 10 + ch] = ex / s2;
}

extern "C" void kernel_launch(void* const* d_in, const int* in_sizes, int n_in,
                              void* d_out, int out_size, void* d_ws, size_t ws_size,
                              hipStream_t stream)
{
    const float* x    = (const float*)d_in[0];
    const int*   ei   = (const int*)d_in[1];
    const float* W1l  = (const float*)d_in[2];
    const float* b1   = (const float*)d_in[3];
    const float* W1r  = (const float*)d_in[4];
    const float* W2l  = (const float*)d_in[5];
    const float* b2   = (const float*)d_in[6];
    const float* W2r  = (const float*)d_in[7];
    const float* Wout = (const float*)d_in[8];
    const float* bout = (const float*)d_in[9];
    float* out = (float*)d_out;

    int n_nodes = in_sizes[0] / 128;
    int n_edges = in_sizes[1] / 2;
    const int* src = ei;
    const int* dst = ei + n_edges;

    // workspace layout (ints first, pad to 16B for float4 regions)
    int* row_ptr = (int*)d_ws;                          // N+1
    int* cnt     = row_ptr + (n_nodes + 1);             // N
    int* cursor  = cnt + n_nodes;                       // N
    int* eid     = cursor + n_nodes;                    // E
    size_t int_count = ((size_t)(3 * n_nodes + 1 + n_edges) + 3) & ~(size_t)3;
    float* y1 = (float*)d_ws + int_count;               // N*32 (16B aligned)
    float* r1 = y1 + (size_t)n_nodes * 32;              // N*32
    float* z2 = r1 + (size_t)n_nodes * 32;              // N*20
    float* r2 = z2 + (size_t)n_nodes * 20;              // N*20

    hipMemsetAsync(cnt, 0, (size_t)n_nodes * sizeof(int), stream);

    int nb_node = (n_nodes + 255) / 256;
    int nb_edge = (n_edges + 255) / 256;
    int nb_grp  = ((n_nodes * 32) + 255) / 256;

    k_lin1<<<nb_node, 256, 0, stream>>>(x, W1l, W1r, y1, r1, n_nodes);
    k_hist<<<nb_edge, 256, 0, stream>>>(dst, cnt, n_edges);
    k_scan<<<1, 1024, 0, stream>>>(cnt, row_ptr, cursor, n_nodes);
    k_fill<<<nb_edge, 256, 0, stream>>>(src, dst, cursor, eid, n_edges);
    k_agg1<<<nb_grp, 256, 0, stream>>>(row_ptr, eid, y1, r1, b1, W2l, W2r, z2, r2, n_nodes);
    k_agg2<<<nb_grp, 256, 0, stream>>>(row_ptr, eid, z2, r2, b2, Wout, bout, out, n_nodes);
}

// Round 3
// 549.649 us; speedup vs baseline: 5.1592x; 2.0325x over previous
//
#include <hip/hip_runtime.h>
#include <math.h>

// GraphSAGE 2-layer, N=100000 nodes, E=3200000 edges
// IN=128, H1=32, H2=20, NCLS=10
// Strategy: aggregate in OUTPUT feature space (linearity commutes with
// segment-mean); CSR-by-dst built via locality-aware 2-level bucketing
// (no full-size hist/scan, no scattered 4B stores to cold lines).

#define BSHIFT 7
#define BS_NODES 128          // nodes per bucket
#define PART_TILE 4096        // edges per k_part block

__global__ __launch_bounds__(256) void k_lin1(
    const float* __restrict__ x, const float* __restrict__ W1l,
    const float* __restrict__ W1r, float* __restrict__ y1,
    float* __restrict__ r1, int n_nodes)
{
    int n = blockIdx.x * 256 + threadIdx.x;
    if (n >= n_nodes) return;
    float accL[32], accR[32];
#pragma unroll
    for (int j = 0; j < 32; ++j) { accL[j] = 0.f; accR[j] = 0.f; }
    const float4* x4 = reinterpret_cast<const float4*>(x) + (size_t)n * 32;
    for (int k4 = 0; k4 < 32; ++k4) {
        float4 xv = x4[k4];
        const float* wl = W1l + k4 * 4 * 32;   // wave-uniform -> scalar loads
        const float* wr = W1r + k4 * 4 * 32;
#pragma unroll
        for (int j = 0; j < 32; ++j) {
            float a = accL[j];
            a = fmaf(xv.x, wl[j],      a);
            a = fmaf(xv.y, wl[32 + j], a);
            a = fmaf(xv.z, wl[64 + j], a);
            a = fmaf(xv.w, wl[96 + j], a);
            accL[j] = a;
            float b = accR[j];
            b = fmaf(xv.x, wr[j],      b);
            b = fmaf(xv.y, wr[32 + j], b);
            b = fmaf(xv.z, wr[64 + j], b);
            b = fmaf(xv.w, wr[96 + j], b);
            accR[j] = b;
        }
    }
    float4* yo = reinterpret_cast<float4*>(y1 + (size_t)n * 32);
    float4* ro = reinterpret_cast<float4*>(r1 + (size_t)n * 32);
#pragma unroll
    for (int q = 0; q < 8; ++q) {
        yo[q] = make_float4(accL[q*4], accL[q*4+1], accL[q*4+2], accL[q*4+3]);
        ro[q] = make_float4(accR[q*4], accR[q*4+1], accR[q*4+2], accR[q*4+3]);
    }
}

// ---- CSR build, stage 0: init bucket cursors to region bases ----
__global__ __launch_bounds__(256) void k_binit(
    int* __restrict__ bcursor, int nb, int capb)
{
    int i = blockIdx.x * 256 + threadIdx.x;
    if (i < nb) bcursor[i] = i * capb;
}

// ---- stage 1: partition edges into per-bucket regions (packed src<<7|local)
//      block-chunked cursor reservation -> coalesced-ish writes ----
__global__ __launch_bounds__(256) void k_part(
    const int* __restrict__ src, const int* __restrict__ dst,
    int* __restrict__ bcursor, int* __restrict__ pairs,
    int n_edges, int nb)
{
    __shared__ int cnt[1024];
    __shared__ int bbase_l[1024];
    int tid = threadIdx.x;
    int ebeg = blockIdx.x * PART_TILE;
    int eend = ebeg + PART_TILE; if (eend > n_edges) eend = n_edges;
    for (int i = tid; i < nb; i += 256) cnt[i] = 0;
    __syncthreads();
    for (int e = ebeg + tid; e < eend; e += 256)
        atomicAdd(&cnt[dst[e] >> BSHIFT], 1);
    __syncthreads();
    for (int i = tid; i < nb; i += 256) {
        int c = cnt[i];
        if (c > 0) bbase_l[i] = atomicAdd(&bcursor[i], c);
    }
    __syncthreads();
    for (int e = ebeg + tid; e < eend; e += 256) {
        int d = dst[e];
        int b = d >> BSHIFT;
        int slot = atomicSub(&cnt[b], 1) - 1;     // countdown ticket
        pairs[(size_t)bbase_l[b] + slot] = (src[e] << BSHIFT) | (d & (BS_NODES - 1));
    }
}

// ---- stage 2: scan bucket counts -> bucket base offsets in final CSR ----
__global__ __launch_bounds__(1024) void k_bscan(
    const int* __restrict__ bcursor, int* __restrict__ bbase,
    int* __restrict__ row_ptr, int nb, int capb, int n_nodes)
{
    __shared__ int sc[1024];
    int t = threadIdx.x;
    int c = (t < nb) ? (bcursor[t] - t * capb) : 0;
    sc[t] = c;
    __syncthreads();
    for (int off = 1; off < 1024; off <<= 1) {
        int v = (t >= off) ? sc[t - off] : 0;
        __syncthreads();
        sc[t] += v;
        __syncthreads();
    }
    if (t < nb) bbase[t] = sc[t] - c;   // exclusive
    if (t == 1023) row_ptr[n_nodes] = sc[t];
}

// ---- stage 3: per-bucket fill: LDS count+scan over 128 nodes, write
//      row_ptr and eid (L2-resident region, no write amplification) ----
__global__ __launch_bounds__(256) void k_bfill(
    const int* __restrict__ pairs, const int* __restrict__ bcursor,
    const int* __restrict__ bbase, int* __restrict__ row_ptr,
    int* __restrict__ eid, int capb, int n_nodes)
{
    __shared__ int cnt128[BS_NODES];
    __shared__ int sc[BS_NODES];
    __shared__ int cur[BS_NODES];
    int b = blockIdx.x;
    int t = threadIdx.x;
    int lo = b * BS_NODES;
    size_t pbeg = (size_t)b * capb;
    int cntE = bcursor[b] - b * capb;
    int base = bbase[b];
    if (t < BS_NODES) cnt128[t] = 0;
    __syncthreads();
    for (int i = t; i < cntE; i += 256)
        atomicAdd(&cnt128[pairs[pbeg + i] & (BS_NODES - 1)], 1);
    __syncthreads();
    int myc = 0;
    if (t < BS_NODES) { myc = cnt128[t]; sc[t] = myc; }
    __syncthreads();
    for (int off = 1; off < BS_NODES; off <<= 1) {
        int v = (t >= off && t < BS_NODES) ? sc[t - off] : 0;
        __syncthreads();
        if (t < BS_NODES) sc[t] += v;
        __syncthreads();
    }
    if (t < BS_NODES) {
        int excl = sc[t] - myc;
        cur[t] = excl;
        if (lo + t < n_nodes) row_ptr[lo + t] = base + excl;
    }
    __syncthreads();
    for (int i = t; i < cntE; i += 256) {
        int p = pairs[pbeg + i];
        int pos = atomicAdd(&cur[p & (BS_NODES - 1)], 1);
        eid[(size_t)base + pos] = p >> BSHIFT;
    }
}

// ---- Layer 1: gather-sum y1 over incoming edges, combine, normalize, relu,
//      project through W2l/W2r. 32 lanes per node (lane = channel). ----
__global__ __launch_bounds__(256) void k_agg1(
    const int* __restrict__ row_ptr, const int* __restrict__ eid,
    const float* __restrict__ y1, const float* __restrict__ r1,
    const float* __restrict__ b1, const float* __restrict__ W2l,
    const float* __restrict__ W2r,
    float* __restrict__ z2, float* __restrict__ r2, int n_nodes)
{
    int t = blockIdx.x * 256 + threadIdx.x;
    int n = t >> 5;
    int ch = t & 31;
    if (n >= n_nodes) return;
    int beg = row_ptr[n], end = row_ptr[n + 1];
    float sum = 0.f;
    for (int i = beg; i < end; ++i) {
        int s = eid[i];                      // same addr across 32 lanes -> broadcast
        sum += y1[(size_t)s * 32 + ch];      // 128B coalesced line per edge
    }
    float inv = 1.0f / fmaxf((float)(end - beg), 1.0f);
    float v = fmaf(sum, inv, b1[ch] + r1[(size_t)n * 32 + ch]);
    float ss = v * v;
#pragma unroll
    for (int off = 16; off >= 1; off >>= 1) ss += __shfl_xor(ss, off, 32);
    float h = fmaxf(v / fmaxf(sqrtf(ss), 1e-12f), 0.f);
    float accl = 0.f, accr = 0.f;
#pragma unroll 4
    for (int i = 0; i < 32; ++i) {
        float hv = __shfl(h, i, 32);
        if (ch < 20) {
            accl = fmaf(hv, W2l[i * 20 + ch], accl);
            accr = fmaf(hv, W2r[i * 20 + ch], accr);
        }
    }
    if (ch < 20) {
        z2[(size_t)n * 20 + ch] = accl;
        r2[(size_t)n * 20 + ch] = accr;
    }
}

// ---- Layer 2: gather-sum z2, combine, normalize, W_out, softmax. ----
__global__ __launch_bounds__(256) void k_agg2(
    const int* __restrict__ row_ptr, const int* __restrict__ eid,
    const float* __restrict__ z2, const float* __restrict__ r2,
    const float* __restrict__ b2, const float* __restrict__ Wout,
    const float* __restrict__ bout,
    float* __restrict__ out, int n_nodes)
{
    int t = blockIdx.x * 256 + threadIdx.x;
    int n = t >> 5;
    int ch = t & 31;
    if (n >= n_nodes) return;
    int beg = row_ptr[n], end = row_ptr[n + 1];
    bool act = ch < 20;
    float sum = 0.f;
    for (int i = beg; i < end; ++i) {
        int s = eid[i];
        if (act) sum += z2[(size_t)s * 20 + ch];
    }
    float inv = 1.0f / fmaxf((float)(end - beg), 1.0f);
    float v = act ? fmaf(sum, inv, b2[ch] + r2[(size_t)n * 20 + ch]) : 0.f;
    float ss = v * v;
#pragma unroll
    for (int off = 16; off >= 1; off >>= 1) ss += __shfl_xor(ss, off, 32);
    float o = v / fmaxf(sqrtf(ss), 1e-12f);
    float acc = (ch < 10) ? bout[ch] : 0.f;
#pragma unroll 4
    for (int i = 0; i < 20; ++i) {
        float ov = __shfl(o, i, 32);
        if (ch < 10) acc = fmaf(ov, Wout[i * 10 + ch], acc);
    }
    float lm = (ch < 10) ? acc : -1e30f;
    float m = lm;
#pragma unroll
    for (int off = 8; off >= 1; off >>= 1) m = fmaxf(m, __shfl_xor(m, off, 16));
    float ex = (ch < 10) ? expf(acc - m) : 0.f;
    float s2 = ex;
#pragma unroll
    for (int off = 8; off >= 1; off >>= 1) s2 += __shfl_xor(s2, off, 16);
    if (ch < 10) out[(size_t)n * 10 + ch] = ex / s2;
}

extern "C" void kernel_launch(void* const* d_in, const int* in_sizes, int n_in,
                              void* d_out, int out_size, void* d_ws, size_t ws_size,
                              hipStream_t stream)
{
    const float* x    = (const float*)d_in[0];
    const int*   ei   = (const int*)d_in[1];
    const float* W1l  = (const float*)d_in[2];
    const float* b1   = (const float*)d_in[3];
    const float* W1r  = (const float*)d_in[4];
    const float* W2l  = (const float*)d_in[5];
    const float* b2   = (const float*)d_in[6];
    const float* W2r  = (const float*)d_in[7];
    const float* Wout = (const float*)d_in[8];
    const float* bout = (const float*)d_in[9];
    float* out = (float*)d_out;

    int n_nodes = in_sizes[0] / 128;
    int n_edges = in_sizes[1] / 2;
    const int* src = ei;
    const int* dst = ei + n_edges;

    int nb = (n_nodes + BS_NODES - 1) / BS_NODES;   // 782 (must be <= 1024)
    double mean = (double)n_edges / nb;
    int capb = (int)(mean + 8.0 * sqrt(mean) + 64.0);
    capb = (capb + 63) & ~63;

    // workspace layout (ints; pairs region aliased by y1.. floats afterwards)
    int* bcursor = (int*)d_ws;                          // nb
    int* bbase   = bcursor + ((nb + 2 + 3) & ~3);       // nb (16B-ish aligned)
    int* row_ptr = bbase + ((nb + 3) & ~3);             // n_nodes+1
    int* eid     = row_ptr + (((n_nodes + 1) + 3) & ~3);// n_edges
    int* pairs   = eid + (((size_t)n_edges + 3) & ~(size_t)3);  // nb*capb

    // floats: y1 aliases pairs (pairs dead before k_lin1 runs)
    float* y1 = (float*)pairs;                          // N*32
    float* r1 = y1 + (size_t)n_nodes * 32;              // N*32
    float* z2 = r1 + (size_t)n_nodes * 32;              // N*20
    float* r2 = z2 + (size_t)n_nodes * 20;              // N*20

    int nb_part = (n_edges + PART_TILE - 1) / PART_TILE;
    int nb_node = (n_nodes + 255) / 256;
    int nb_grp  = ((n_nodes * 32) + 255) / 256;

    k_binit<<<(nb + 255) / 256, 256, 0, stream>>>(bcursor, nb, capb);
    k_part<<<nb_part, 256, 0, stream>>>(src, dst, bcursor, pairs, n_edges, nb);
    k_bscan<<<1, 1024, 0, stream>>>(bcursor, bbase, row_ptr, nb, capb, n_nodes);
    k_bfill<<<nb, 256, 0, stream>>>(pairs, bcursor, bbase, row_ptr, eid, capb, n_nodes);
    k_lin1<<<nb_node, 256, 0, stream>>>(x, W1l, W1r, y1, r1, n_nodes);
    k_agg1<<<nb_grp, 256, 0, stream>>>(row_ptr, eid, y1, r1, b1, W2l, W2r, z2, r2, n_nodes);
    k_agg2<<<nb_grp, 256, 0, stream>>>(row_ptr, eid, z2, r2, b2, Wout, bout, out, n_nodes);
}

// Round 4
// 529.453 us; speedup vs baseline: 5.3560x; 1.0381x over previous
//
#include <hip/hip_runtime.h>
#include <hip/hip_fp16.h>
#include <math.h>

// GraphSAGE 2-layer, N=100000 nodes, E=3200000 edges
// IN=128, H1=32, H2=20, NCLS=10
// Aggregate in OUTPUT feature space; CSR-by-dst via 2-level bucketing;
// gather tables (y1, z2) stored fp16 with 64B-aligned rows -> 1 line/edge.

#define BSHIFT 7
#define BS_NODES 128          // nodes per bucket
#define PART_TILE 4096        // edges per k_part block

__global__ __launch_bounds__(256) void k_lin1(
    const float* __restrict__ x, const float* __restrict__ W1l,
    const float* __restrict__ W1r, __half* __restrict__ y1,
    float* __restrict__ r1, int n_nodes)
{
    int n = blockIdx.x * 256 + threadIdx.x;
    if (n >= n_nodes) return;
    float accL[32], accR[32];
#pragma unroll
    for (int j = 0; j < 32; ++j) { accL[j] = 0.f; accR[j] = 0.f; }
    const float4* x4 = reinterpret_cast<const float4*>(x) + (size_t)n * 32;
    for (int k4 = 0; k4 < 32; ++k4) {
        float4 xv = x4[k4];
        const float* wl = W1l + k4 * 4 * 32;   // wave-uniform -> scalar loads
        const float* wr = W1r + k4 * 4 * 32;
#pragma unroll
        for (int j = 0; j < 32; ++j) {
            float a = accL[j];
            a = fmaf(xv.x, wl[j],      a);
            a = fmaf(xv.y, wl[32 + j], a);
            a = fmaf(xv.z, wl[64 + j], a);
            a = fmaf(xv.w, wl[96 + j], a);
            accL[j] = a;
            float b = accR[j];
            b = fmaf(xv.x, wr[j],      b);
            b = fmaf(xv.y, wr[32 + j], b);
            b = fmaf(xv.z, wr[64 + j], b);
            b = fmaf(xv.w, wr[96 + j], b);
            accR[j] = b;
        }
    }
    // y1 row: 32 halfs = 64B, one cache line
    unsigned upk[16];
#pragma unroll
    for (int q = 0; q < 16; ++q) {
        __half2 h = __floats2half2_rn(accL[2*q], accL[2*q+1]);
        upk[q] = *reinterpret_cast<unsigned*>(&h);
    }
    uint4* yo = reinterpret_cast<uint4*>(y1 + (size_t)n * 32);
#pragma unroll
    for (int q = 0; q < 4; ++q)
        yo[q] = make_uint4(upk[4*q], upk[4*q+1], upk[4*q+2], upk[4*q+3]);
    float4* ro = reinterpret_cast<float4*>(r1 + (size_t)n * 32);
#pragma unroll
    for (int q = 0; q < 8; ++q)
        ro[q] = make_float4(accR[q*4], accR[q*4+1], accR[q*4+2], accR[q*4+3]);
}

// ---- CSR build, stage 0: init bucket cursors to region bases ----
__global__ __launch_bounds__(256) void k_binit(
    int* __restrict__ bcursor, int nb, int capb)
{
    int i = blockIdx.x * 256 + threadIdx.x;
    if (i < nb) bcursor[i] = i * capb;
}

// ---- stage 1: partition edges into per-bucket regions ----
__global__ __launch_bounds__(256) void k_part(
    const int* __restrict__ src, const int* __restrict__ dst,
    int* __restrict__ bcursor, int* __restrict__ pairs,
    int n_edges, int nb)
{
    __shared__ int cnt[1024];
    __shared__ int bbase_l[1024];
    int tid = threadIdx.x;
    int ebeg = blockIdx.x * PART_TILE;
    int eend = ebeg + PART_TILE; if (eend > n_edges) eend = n_edges;
    for (int i = tid; i < nb; i += 256) cnt[i] = 0;
    __syncthreads();
    for (int e = ebeg + tid; e < eend; e += 256)
        atomicAdd(&cnt[dst[e] >> BSHIFT], 1);
    __syncthreads();
    for (int i = tid; i < nb; i += 256) {
        int c = cnt[i];
        if (c > 0) bbase_l[i] = atomicAdd(&bcursor[i], c);
    }
    __syncthreads();
    for (int e = ebeg + tid; e < eend; e += 256) {
        int d = dst[e];
        int b = d >> BSHIFT;
        int slot = atomicSub(&cnt[b], 1) - 1;     // countdown ticket
        pairs[(size_t)bbase_l[b] + slot] = (src[e] << BSHIFT) | (d & (BS_NODES - 1));
    }
}

// ---- stage 2: scan bucket counts -> bucket base offsets ----
__global__ __launch_bounds__(1024) void k_bscan(
    const int* __restrict__ bcursor, int* __restrict__ bbase,
    int* __restrict__ row_ptr, int nb, int capb, int n_nodes)
{
    __shared__ int sc[1024];
    int t = threadIdx.x;
    int c = (t < nb) ? (bcursor[t] - t * capb) : 0;
    sc[t] = c;
    __syncthreads();
    for (int off = 1; off < 1024; off <<= 1) {
        int v = (t >= off) ? sc[t - off] : 0;
        __syncthreads();
        sc[t] += v;
        __syncthreads();
    }
    if (t < nb) bbase[t] = sc[t] - c;   // exclusive
    if (t == 1023) row_ptr[n_nodes] = sc[t];
}

// ---- stage 3: per-bucket fill of row_ptr + eid ----
__global__ __launch_bounds__(256) void k_bfill(
    const int* __restrict__ pairs, const int* __restrict__ bcursor,
    const int* __restrict__ bbase, int* __restrict__ row_ptr,
    int* __restrict__ eid, int capb, int n_nodes)
{
    __shared__ int cnt128[BS_NODES];
    __shared__ int sc[BS_NODES];
    __shared__ int cur[BS_NODES];
    int b = blockIdx.x;
    int t = threadIdx.x;
    int lo = b * BS_NODES;
    size_t pbeg = (size_t)b * capb;
    int cntE = bcursor[b] - b * capb;
    int base = bbase[b];
    if (t < BS_NODES) cnt128[t] = 0;
    __syncthreads();
    for (int i = t; i < cntE; i += 256)
        atomicAdd(&cnt128[pairs[pbeg + i] & (BS_NODES - 1)], 1);
    __syncthreads();
    int myc = 0;
    if (t < BS_NODES) { myc = cnt128[t]; sc[t] = myc; }
    __syncthreads();
    for (int off = 1; off < BS_NODES; off <<= 1) {
        int v = (t >= off && t < BS_NODES) ? sc[t - off] : 0;
        __syncthreads();
        if (t < BS_NODES) sc[t] += v;
        __syncthreads();
    }
    if (t < BS_NODES) {
        int excl = sc[t] - myc;
        cur[t] = excl;
        if (lo + t < n_nodes) row_ptr[lo + t] = base + excl;
    }
    __syncthreads();
    for (int i = t; i < cntE; i += 256) {
        int p = pairs[pbeg + i];
        int pos = atomicAdd(&cur[p & (BS_NODES - 1)], 1);
        eid[(size_t)base + pos] = p >> BSHIFT;
    }
}

// ---- Layer 1: gather-sum fp16 y1, combine, normalize, relu, project ----
__global__ __launch_bounds__(256) void k_agg1(
    const int* __restrict__ row_ptr, const int* __restrict__ eid,
    const __half* __restrict__ y1, const float* __restrict__ r1,
    const float* __restrict__ b1, const float* __restrict__ W2l,
    const float* __restrict__ W2r,
    __half* __restrict__ z2, float* __restrict__ r2, int n_nodes)
{
    int t = blockIdx.x * 256 + threadIdx.x;
    int n = t >> 5;
    int ch = t & 31;
    if (n >= n_nodes) return;
    int beg = row_ptr[n], end = row_ptr[n + 1];
    float sum = 0.f;
    for (int i = beg; i < end; ++i) {
        int s = eid[i];                      // broadcast across 32 lanes
        sum += __half2float(y1[(size_t)s * 32 + ch]);  // 64B line per edge
    }
    float inv = 1.0f / fmaxf((float)(end - beg), 1.0f);
    float v = fmaf(sum, inv, b1[ch] + r1[(size_t)n * 32 + ch]);
    float ss = v * v;
#pragma unroll
    for (int off = 16; off >= 1; off >>= 1) ss += __shfl_xor(ss, off, 32);
    float h = fmaxf(v / fmaxf(sqrtf(ss), 1e-12f), 0.f);
    float accl = 0.f, accr = 0.f;
#pragma unroll 4
    for (int i = 0; i < 32; ++i) {
        float hv = __shfl(h, i, 32);
        if (ch < 20) {
            accl = fmaf(hv, W2l[i * 20 + ch], accl);
            accr = fmaf(hv, W2r[i * 20 + ch], accr);
        }
    }
    // z2 row padded to 32 halfs (64B line); pad lanes write zero
    z2[(size_t)n * 32 + ch] = __float2half(ch < 20 ? accl : 0.f);
    if (ch < 20) r2[(size_t)n * 20 + ch] = accr;
}

// ---- Layer 2: gather-sum fp16 z2, combine, normalize, W_out, softmax ----
__global__ __launch_bounds__(256) void k_agg2(
    const int* __restrict__ row_ptr, const int* __restrict__ eid,
    const __half* __restrict__ z2, const float* __restrict__ r2,
    const float* __restrict__ b2, const float* __restrict__ Wout,
    const float* __restrict__ bout,
    float* __restrict__ out, int n_nodes)
{
    int t = blockIdx.x * 256 + threadIdx.x;
    int n = t >> 5;
    int ch = t & 31;
    if (n >= n_nodes) return;
    int beg = row_ptr[n], end = row_ptr[n + 1];
    bool act = ch < 20;
    float sum = 0.f;
    for (int i = beg; i < end; ++i) {
        int s = eid[i];
        sum += __half2float(z2[(size_t)s * 32 + ch]);  // 64B line; pads add 0
    }
    float inv = 1.0f / fmaxf((float)(end - beg), 1.0f);
    float v = act ? fmaf(sum, inv, b2[ch] + r2[(size_t)n * 20 + ch]) : 0.f;
    float ss = v * v;
#pragma unroll
    for (int off = 16; off >= 1; off >>= 1) ss += __shfl_xor(ss, off, 32);
    float o = v / fmaxf(sqrtf(ss), 1e-12f);
    float acc = (ch < 10) ? bout[ch] : 0.f;
#pragma unroll 4
    for (int i = 0; i < 20; ++i) {
        float ov = __shfl(o, i, 32);
        if (ch < 10) acc = fmaf(ov, Wout[i * 10 + ch], acc);
    }
    float lm = (ch < 10) ? acc : -1e30f;
    float m = lm;
#pragma unroll
    for (int off = 8; off >= 1; off >>= 1) m = fmaxf(m, __shfl_xor(m, off, 16));
    float ex = (ch < 10) ? expf(acc - m) : 0.f;
    float s2 = ex;
#pragma unroll
    for (int off = 8; off >= 1; off >>= 1) s2 += __shfl_xor(s2, off, 16);
    if (ch < 10) out[(size_t)n * 10 + ch] = ex / s2;
}

extern "C" void kernel_launch(void* const* d_in, const int* in_sizes, int n_in,
                              void* d_out, int out_size, void* d_ws, size_t ws_size,
                              hipStream_t stream)
{
    const float* x    = (const float*)d_in[0];
    const int*   ei   = (const int*)d_in[1];
    const float* W1l  = (const float*)d_in[2];
    const float* b1   = (const float*)d_in[3];
    const float* W1r  = (const float*)d_in[4];
    const float* W2l  = (const float*)d_in[5];
    const float* b2   = (const float*)d_in[6];
    const float* W2r  = (const float*)d_in[7];
    const float* Wout = (const float*)d_in[8];
    const float* bout = (const float*)d_in[9];
    float* out = (float*)d_out;

    int n_nodes = in_sizes[0] / 128;
    int n_edges = in_sizes[1] / 2;
    const int* src = ei;
    const int* dst = ei + n_edges;

    int nb = (n_nodes + BS_NODES - 1) / BS_NODES;   // 782 (<= 1024)
    double mean = (double)n_edges / nb;
    int capb = (int)(mean + 8.0 * sqrt(mean) + 64.0);
    capb = (capb + 63) & ~63;

    // workspace layout
    int* bcursor = (int*)d_ws;                          // nb
    int* bbase   = bcursor + ((nb + 2 + 3) & ~3);       // nb
    int* row_ptr = bbase + ((nb + 3) & ~3);             // n_nodes+1
    int* eid     = row_ptr + (((n_nodes + 1) + 3) & ~3);// n_edges
    int* pairs   = eid + (((size_t)n_edges + 3) & ~(size_t)3);  // nb*capb

    // fp16 gather tables; y1 aliases pairs (pairs dead before k_lin1 runs)
    __half* y1 = (__half*)pairs;                        // N*32 halfs (64B rows)
    float*  r1 = (float*)(y1 + (size_t)n_nodes * 32);   // N*32 f32
    __half* z2 = (__half*)(r1 + (size_t)n_nodes * 32);  // N*32 halfs (64B rows, 20 used)
    float*  r2 = (float*)(z2 + (size_t)n_nodes * 32);   // N*20 f32

    int nb_part = (n_edges + PART_TILE - 1) / PART_TILE;
    int nb_node = (n_nodes + 255) / 256;
    int nb_grp  = ((n_nodes * 32) + 255) / 256;

    k_binit<<<(nb + 255) / 256, 256, 0, stream>>>(bcursor, nb, capb);
    k_part<<<nb_part, 256, 0, stream>>>(src, dst, bcursor, pairs, n_edges, nb);
    k_bscan<<<1, 1024, 0, stream>>>(bcursor, bbase, row_ptr, nb, capb, n_nodes);
    k_bfill<<<nb, 256, 0, stream>>>(pairs, bcursor, bbase, row_ptr, eid, capb, n_nodes);
    k_lin1<<<nb_node, 256, 0, stream>>>(x, W1l, W1r, y1, r1, n_nodes);
    k_agg1<<<nb_grp, 256, 0, stream>>>(row_ptr, eid, y1, r1, b1, W2l, W2r, z2, r2, n_nodes);
    k_agg2<<<nb_grp, 256, 0, stream>>>(row_ptr, eid, z2, r2, b2, Wout, bout, out, n_nodes);
}

// Round 5
// 404.820 us; speedup vs baseline: 7.0050x; 1.3079x over previous
//
#include <hip/hip_runtime.h>
#include <hip/hip_fp16.h>
#include <math.h>

// GraphSAGE 2-layer, N=100000 nodes, E=3200000 edges
// IN=128, H1=32, H2=20, NCLS=10
// Aggregate in OUTPUT feature space; CSR-by-dst via 2-level bucketing;
// fp16 gather tables with 64B rows; gather loop unrolled x4 for MLP;
// nontemporal streaming loads to keep L2 for the gather table.

#define BSHIFT 7
#define BS_NODES 128          // nodes per bucket
#define PART_TILE 4096        // edges per k_part block

__global__ __launch_bounds__(256) void k_lin1(
    const float* __restrict__ x, const float* __restrict__ W1l,
    const float* __restrict__ W1r, __half* __restrict__ y1,
    float* __restrict__ r1, int n_nodes)
{
    int n = blockIdx.x * 256 + threadIdx.x;
    if (n >= n_nodes) return;
    float accL[32], accR[32];
#pragma unroll
    for (int j = 0; j < 32; ++j) { accL[j] = 0.f; accR[j] = 0.f; }
    const float4* x4 = reinterpret_cast<const float4*>(x) + (size_t)n * 32;
    for (int k4 = 0; k4 < 32; ++k4) {
        float4 xv = x4[k4];
        const float* wl = W1l + k4 * 4 * 32;   // wave-uniform -> scalar loads
        const float* wr = W1r + k4 * 4 * 32;
#pragma unroll
        for (int j = 0; j < 32; ++j) {
            float a = accL[j];
            a = fmaf(xv.x, wl[j],      a);
            a = fmaf(xv.y, wl[32 + j], a);
            a = fmaf(xv.z, wl[64 + j], a);
            a = fmaf(xv.w, wl[96 + j], a);
            accL[j] = a;
            float b = accR[j];
            b = fmaf(xv.x, wr[j],      b);
            b = fmaf(xv.y, wr[32 + j], b);
            b = fmaf(xv.z, wr[64 + j], b);
            b = fmaf(xv.w, wr[96 + j], b);
            accR[j] = b;
        }
    }
    unsigned upk[16];
#pragma unroll
    for (int q = 0; q < 16; ++q) {
        __half2 h = __floats2half2_rn(accL[2*q], accL[2*q+1]);
        upk[q] = *reinterpret_cast<unsigned*>(&h);
    }
    uint4* yo = reinterpret_cast<uint4*>(y1 + (size_t)n * 32);
#pragma unroll
    for (int q = 0; q < 4; ++q)
        yo[q] = make_uint4(upk[4*q], upk[4*q+1], upk[4*q+2], upk[4*q+3]);
    float4* ro = reinterpret_cast<float4*>(r1 + (size_t)n * 32);
#pragma unroll
    for (int q = 0; q < 8; ++q)
        ro[q] = make_float4(accR[q*4], accR[q*4+1], accR[q*4+2], accR[q*4+3]);
}

// ---- CSR build, stage 0 ----
__global__ __launch_bounds__(256) void k_binit(
    int* __restrict__ bcursor, int nb, int capb)
{
    int i = blockIdx.x * 256 + threadIdx.x;
    if (i < nb) bcursor[i] = i * capb;
}

// ---- stage 1: partition edges into per-bucket regions ----
__global__ __launch_bounds__(256) void k_part(
    const int* __restrict__ src, const int* __restrict__ dst,
    int* __restrict__ bcursor, int* __restrict__ pairs,
    int n_edges, int nb)
{
    __shared__ int cnt[1024];
    __shared__ int bbase_l[1024];
    int tid = threadIdx.x;
    int ebeg = blockIdx.x * PART_TILE;
    int eend = ebeg + PART_TILE; if (eend > n_edges) eend = n_edges;
    for (int i = tid; i < nb; i += 256) cnt[i] = 0;
    __syncthreads();
    for (int e = ebeg + tid; e < eend; e += 256)
        atomicAdd(&cnt[dst[e] >> BSHIFT], 1);
    __syncthreads();
    for (int i = tid; i < nb; i += 256) {
        int c = cnt[i];
        if (c > 0) bbase_l[i] = atomicAdd(&bcursor[i], c);
    }
    __syncthreads();
    for (int e = ebeg + tid; e < eend; e += 256) {
        int d = dst[e];
        int b = d >> BSHIFT;
        int slot = atomicSub(&cnt[b], 1) - 1;     // countdown ticket
        pairs[(size_t)bbase_l[b] + slot] = (src[e] << BSHIFT) | (d & (BS_NODES - 1));
    }
}

// ---- stage 2: scan bucket counts ----
__global__ __launch_bounds__(1024) void k_bscan(
    const int* __restrict__ bcursor, int* __restrict__ bbase,
    int* __restrict__ row_ptr, int nb, int capb, int n_nodes)
{
    __shared__ int sc[1024];
    int t = threadIdx.x;
    int c = (t < nb) ? (bcursor[t] - t * capb) : 0;
    sc[t] = c;
    __syncthreads();
    for (int off = 1; off < 1024; off <<= 1) {
        int v = (t >= off) ? sc[t - off] : 0;
        __syncthreads();
        sc[t] += v;
        __syncthreads();
    }
    if (t < nb) bbase[t] = sc[t] - c;   // exclusive
    if (t == 1023) row_ptr[n_nodes] = sc[t];
}

// ---- stage 3: per-bucket fill of row_ptr + eid ----
__global__ __launch_bounds__(256) void k_bfill(
    const int* __restrict__ pairs, const int* __restrict__ bcursor,
    const int* __restrict__ bbase, int* __restrict__ row_ptr,
    int* __restrict__ eid, int capb, int n_nodes)
{
    __shared__ int cnt128[BS_NODES];
    __shared__ int sc[BS_NODES];
    __shared__ int cur[BS_NODES];
    int b = blockIdx.x;
    int t = threadIdx.x;
    int lo = b * BS_NODES;
    size_t pbeg = (size_t)b * capb;
    int cntE = bcursor[b] - b * capb;
    int base = bbase[b];
    if (t < BS_NODES) cnt128[t] = 0;
    __syncthreads();
    for (int i = t; i < cntE; i += 256)
        atomicAdd(&cnt128[pairs[pbeg + i] & (BS_NODES - 1)], 1);
    __syncthreads();
    int myc = 0;
    if (t < BS_NODES) { myc = cnt128[t]; sc[t] = myc; }
    __syncthreads();
    for (int off = 1; off < BS_NODES; off <<= 1) {
        int v = (t >= off && t < BS_NODES) ? sc[t - off] : 0;
        __syncthreads();
        if (t < BS_NODES) sc[t] += v;
        __syncthreads();
    }
    if (t < BS_NODES) {
        int excl = sc[t] - myc;
        cur[t] = excl;
        if (lo + t < n_nodes) row_ptr[lo + t] = base + excl;
    }
    __syncthreads();
    for (int i = t; i < cntE; i += 256) {
        int p = pairs[pbeg + i];
        int pos = atomicAdd(&cur[p & (BS_NODES - 1)], 1);
        eid[(size_t)base + pos] = p >> BSHIFT;
    }
}

// ---- Layer 1: gather-sum fp16 y1 (x4 unrolled), combine, norm, project ----
__global__ __launch_bounds__(256) void k_agg1(
    const int* __restrict__ row_ptr, const int* __restrict__ eid,
    const __half* __restrict__ y1, const float* __restrict__ r1,
    const float* __restrict__ b1, const float* __restrict__ W2l,
    const float* __restrict__ W2r,
    __half* __restrict__ z2, float* __restrict__ r2, int n_nodes)
{
    int t = blockIdx.x * 256 + threadIdx.x;
    int n = t >> 5;
    int ch = t & 31;
    if (n >= n_nodes) return;
    int beg = row_ptr[n], end = row_ptr[n + 1];
    float s0 = 0.f, s1 = 0.f, s2 = 0.f, s3 = 0.f;
    int i = beg;
    for (; i + 4 <= end; i += 4) {
        int e0 = __builtin_nontemporal_load(&eid[i]);
        int e1 = __builtin_nontemporal_load(&eid[i + 1]);
        int e2 = __builtin_nontemporal_load(&eid[i + 2]);
        int e3 = __builtin_nontemporal_load(&eid[i + 3]);
        s0 += __half2float(y1[(size_t)e0 * 32 + ch]);
        s1 += __half2float(y1[(size_t)e1 * 32 + ch]);
        s2 += __half2float(y1[(size_t)e2 * 32 + ch]);
        s3 += __half2float(y1[(size_t)e3 * 32 + ch]);
    }
    for (; i < end; ++i) {
        int e = __builtin_nontemporal_load(&eid[i]);
        s0 += __half2float(y1[(size_t)e * 32 + ch]);
    }
    float sum = (s0 + s1) + (s2 + s3);
    float inv = 1.0f / fmaxf((float)(end - beg), 1.0f);
    float rself = __builtin_nontemporal_load(&r1[(size_t)n * 32 + ch]);
    float v = fmaf(sum, inv, b1[ch] + rself);
    float ss = v * v;
#pragma unroll
    for (int off = 16; off >= 1; off >>= 1) ss += __shfl_xor(ss, off, 32);
    float h = fmaxf(v / fmaxf(sqrtf(ss), 1e-12f), 0.f);
    float accl = 0.f, accr = 0.f;
#pragma unroll 4
    for (int ii = 0; ii < 32; ++ii) {
        float hv = __shfl(h, ii, 32);
        if (ch < 20) {
            accl = fmaf(hv, W2l[ii * 20 + ch], accl);
            accr = fmaf(hv, W2r[ii * 20 + ch], accr);
        }
    }
    z2[(size_t)n * 32 + ch] = __float2half(ch < 20 ? accl : 0.f);
    if (ch < 20) r2[(size_t)n * 20 + ch] = accr;
}

// ---- Layer 2: gather-sum fp16 z2 (x4 unrolled), combine, norm, softmax ----
__global__ __launch_bounds__(256) void k_agg2(
    const int* __restrict__ row_ptr, const int* __restrict__ eid,
    const __half* __restrict__ z2, const float* __restrict__ r2,
    const float* __restrict__ b2, const float* __restrict__ Wout,
    const float* __restrict__ bout,
    float* __restrict__ out, int n_nodes)
{
    int t = blockIdx.x * 256 + threadIdx.x;
    int n = t >> 5;
    int ch = t & 31;
    if (n >= n_nodes) return;
    int beg = row_ptr[n], end = row_ptr[n + 1];
    bool act = ch < 20;
    float s0 = 0.f, s1 = 0.f, s2 = 0.f, s3 = 0.f;
    int i = beg;
    for (; i + 4 <= end; i += 4) {
        int e0 = __builtin_nontemporal_load(&eid[i]);
        int e1 = __builtin_nontemporal_load(&eid[i + 1]);
        int e2 = __builtin_nontemporal_load(&eid[i + 2]);
        int e3 = __builtin_nontemporal_load(&eid[i + 3]);
        s0 += __half2float(z2[(size_t)e0 * 32 + ch]);
        s1 += __half2float(z2[(size_t)e1 * 32 + ch]);
        s2 += __half2float(z2[(size_t)e2 * 32 + ch]);
        s3 += __half2float(z2[(size_t)e3 * 32 + ch]);
    }
    for (; i < end; ++i) {
        int e = __builtin_nontemporal_load(&eid[i]);
        s0 += __half2float(z2[(size_t)e * 32 + ch]);
    }
    float sum = (s0 + s1) + (s2 + s3);
    float inv = 1.0f / fmaxf((float)(end - beg), 1.0f);
    float rself = act ? __builtin_nontemporal_load(&r2[(size_t)n * 20 + ch]) : 0.f;
    float v = act ? fmaf(sum, inv, b2[ch] + rself) : 0.f;
    float ss = v * v;
#pragma unroll
    for (int off = 16; off >= 1; off >>= 1) ss += __shfl_xor(ss, off, 32);
    float o = v / fmaxf(sqrtf(ss), 1e-12f);
    float acc = (ch < 10) ? bout[ch] : 0.f;
#pragma unroll 4
    for (int ii = 0; ii < 20; ++ii) {
        float ov = __shfl(o, ii, 32);
        if (ch < 10) acc = fmaf(ov, Wout[ii * 10 + ch], acc);
    }
    float lm = (ch < 10) ? acc : -1e30f;
    float m = lm;
#pragma unroll
    for (int off = 8; off >= 1; off >>= 1) m = fmaxf(m, __shfl_xor(m, off, 16));
    float ex = (ch < 10) ? expf(acc - m) : 0.f;
    float s2r = ex;
#pragma unroll
    for (int off = 8; off >= 1; off >>= 1) s2r += __shfl_xor(s2r, off, 16);
    if (ch < 10) out[(size_t)n * 10 + ch] = ex / s2r;
}

extern "C" void kernel_launch(void* const* d_in, const int* in_sizes, int n_in,
                              void* d_out, int out_size, void* d_ws, size_t ws_size,
                              hipStream_t stream)
{
    const float* x    = (const float*)d_in[0];
    const int*   ei   = (const int*)d_in[1];
    const float* W1l  = (const float*)d_in[2];
    const float* b1   = (const float*)d_in[3];
    const float* W1r  = (const float*)d_in[4];
    const float* W2l  = (const float*)d_in[5];
    const float* b2   = (const float*)d_in[6];
    const float* W2r  = (const float*)d_in[7];
    const float* Wout = (const float*)d_in[8];
    const float* bout = (const float*)d_in[9];
    float* out = (float*)d_out;

    int n_nodes = in_sizes[0] / 128;
    int n_edges = in_sizes[1] / 2;
    const int* src = ei;
    const int* dst = ei + n_edges;

    int nb = (n_nodes + BS_NODES - 1) / BS_NODES;   // 782 (<= 1024)
    double mean = (double)n_edges / nb;
    int capb = (int)(mean + 8.0 * sqrt(mean) + 64.0);
    capb = (capb + 63) & ~63;

    // workspace layout
    int* bcursor = (int*)d_ws;                          // nb
    int* bbase   = bcursor + ((nb + 2 + 3) & ~3);       // nb
    int* row_ptr = bbase + ((nb + 3) & ~3);             // n_nodes+1
    int* eid     = row_ptr + (((n_nodes + 1) + 3) & ~3);// n_edges
    int* pairs   = eid + (((size_t)n_edges + 3) & ~(size_t)3);  // nb*capb

    // fp16 gather tables; y1 aliases pairs (pairs dead before k_lin1 runs)
    __half* y1 = (__half*)pairs;                        // N*32 halfs (64B rows)
    float*  r1 = (float*)(y1 + (size_t)n_nodes * 32);   // N*32 f32
    __half* z2 = (__half*)(r1 + (size_t)n_nodes * 32);  // N*32 halfs (64B rows, 20 used)
    float*  r2 = (float*)(z2 + (size_t)n_nodes * 32);   // N*20 f32

    int nb_part = (n_edges + PART_TILE - 1) / PART_TILE;
    int nb_node = (n_nodes + 255) / 256;
    int nb_grp  = ((n_nodes * 32) + 255) / 256;

    k_binit<<<(nb + 255) / 256, 256, 0, stream>>>(bcursor, nb, capb);
    k_part<<<nb_part, 256, 0, stream>>>(src, dst, bcursor, pairs, n_edges, nb);
    k_bscan<<<1, 1024, 0, stream>>>(bcursor, bbase, row_ptr, nb, capb, n_nodes);
    k_bfill<<<nb, 256, 0, stream>>>(pairs, bcursor, bbase, row_ptr, eid, capb, n_nodes);
    k_lin1<<<nb_node, 256, 0, stream>>>(x, W1l, W1r, y1, r1, n_nodes);
    k_agg1<<<nb_grp, 256, 0, stream>>>(row_ptr, eid, y1, r1, b1, W2l, W2r, z2, r2, n_nodes);
    k_agg2<<<nb_grp, 256, 0, stream>>>(row_ptr, eid, z2, r2, b2, Wout, bout, out, n_nodes);
}